// Round 1
// baseline (595.206 us; speedup 1.0000x reference)
//
#include <hip/hip_runtime.h>
#include <math.h>

#define MTOT 8192   // B*N
#define HD   512    // hidden dim
#define NEG  0.2f   // leaky relu slope

// ---------------- CSR build ----------------

__global__ void zero_ints(int* p, int n) {
    int i = blockIdx.x * 256 + threadIdx.x;
    if (i < n) p[i] = 0;
}

__global__ void count_deg(const int* __restrict__ dst, int* __restrict__ deg, int E) {
    int i = blockIdx.x * 256 + threadIdx.x;
    if (i < E) atomicAdd(&deg[dst[i]], 1);
}

// single block, 1024 threads, 8 elems each -> exclusive offsets over 8192 nodes
__global__ __launch_bounds__(1024) void scan_offsets(const int* __restrict__ deg,
                                                     int* __restrict__ offs,
                                                     int* __restrict__ cursor) {
    __shared__ int part[1024];
    int tid = threadIdx.x;
    int base = tid * 8;
    int v[8]; int s = 0;
    #pragma unroll
    for (int i = 0; i < 8; ++i) { v[i] = deg[base + i]; s += v[i]; }
    part[tid] = s;
    __syncthreads();
    for (int off = 1; off < 1024; off <<= 1) {
        int t = (tid >= off) ? part[tid - off] : 0;
        __syncthreads();
        part[tid] += t;
        __syncthreads();
    }
    int run = (tid == 0) ? 0 : part[tid - 1];
    #pragma unroll
    for (int i = 0; i < 8; ++i) {
        offs[base + i] = run;
        cursor[base + i] = run;
        run += v[i];
    }
    if (tid == 1023) offs[MTOT] = run;
}

__global__ void scatter_edges(const int* __restrict__ src, const int* __restrict__ dst,
                              int* __restrict__ cursor, int* __restrict__ csr_src, int E) {
    int i = blockIdx.x * 256 + threadIdx.x;
    if (i < E) {
        int p = atomicAdd(&cursor[dst[i]], 1);
        csr_src[p] = src[i];
    }
}

// ---------------- dual GEMM: xl = X@Wl + bl ; xr = X@Wr + br ----------------
// blockIdx.z selects (Wl,bl,xl) vs (Wr,br,xr). 64x64 tile, BK=16, 256 thr, 4x4/thread.

__global__ __launch_bounds__(256) void gemm_dual(
    const float* __restrict__ X,
    const float* __restrict__ Wl, const float* __restrict__ bl,
    const float* __restrict__ Wr, const float* __restrict__ br,
    float* __restrict__ xl, float* __restrict__ xr) {
    const float* W  = blockIdx.z ? Wr : Wl;
    const float* bv = blockIdx.z ? br : bl;
    float* C        = blockIdx.z ? xr : xl;

    __shared__ float Xs[16][68];   // [k][m], pad 68 keeps float4 alignment (272B rows)
    __shared__ float Ws[16][64];   // [k][n]

    int tid = threadIdx.x;
    int bm = blockIdx.y * 64, bn = blockIdx.x * 64;
    int tx = tid & 15, ty = tid >> 4;

    float acc[4][4] = {};

    for (int k0 = 0; k0 < HD; k0 += 16) {
        {   // stage X tile (64 M x 16 K), transpose into [k][m]
            int row = tid >> 2;
            int kc  = (tid & 3) << 2;
            float4 v = *(const float4*)(X + (size_t)(bm + row) * HD + k0 + kc);
            Xs[kc + 0][row] = v.x; Xs[kc + 1][row] = v.y;
            Xs[kc + 2][row] = v.z; Xs[kc + 3][row] = v.w;
        }
        {   // stage W tile (16 K x 64 N)
            int kr = tid >> 4;
            int nc = (tid & 15) << 2;
            *(float4*)(&Ws[kr][nc]) = *(const float4*)(W + (size_t)(k0 + kr) * HD + bn + nc);
        }
        __syncthreads();
        #pragma unroll
        for (int k = 0; k < 16; ++k) {
            float4 av = *(const float4*)(&Xs[k][ty << 2]);
            float4 bw = *(const float4*)(&Ws[k][tx << 2]);
            float a_[4] = {av.x, av.y, av.z, av.w};
            float b_[4] = {bw.x, bw.y, bw.z, bw.w};
            #pragma unroll
            for (int i = 0; i < 4; ++i)
                #pragma unroll
                for (int j = 0; j < 4; ++j)
                    acc[i][j] += a_[i] * b_[j];
        }
        __syncthreads();
    }

    float4 bb = *(const float4*)(bv + bn + (tx << 2));
    #pragma unroll
    for (int i = 0; i < 4; ++i) {
        float4 o;
        o.x = acc[i][0] + bb.x; o.y = acc[i][1] + bb.y;
        o.z = acc[i][2] + bb.z; o.w = acc[i][3] + bb.w;
        *(float4*)(C + (size_t)(bm + (ty << 2) + i) * HD + bn + (tx << 2)) = o;
    }
}

// ---------------- per-node online-softmax aggregation ----------------
// One wave (64 lanes) per node; each lane owns 8 features (2 float4 chunks).

__global__ __launch_bounds__(256) void gat_aggregate(
    const float* __restrict__ xl, const float* __restrict__ xr,
    const float* __restrict__ avec, const float* __restrict__ bias,
    const int* __restrict__ offs, const int* __restrict__ csr_src,
    float* __restrict__ out) {
    int node = (blockIdx.x << 2) + (threadIdx.x >> 6);
    int lane = threadIdx.x & 63;
    int h0 = lane << 2;           // chunk 0 at h0, chunk 1 at h0+256

    float4 a0 = *(const float4*)(avec + h0);
    float4 a1 = *(const float4*)(avec + 256 + h0);
    const float* xrrow = xr + (size_t)node * HD;
    float4 r0 = *(const float4*)(xrrow + h0);
    float4 r1 = *(const float4*)(xrrow + 256 + h0);

    float4 acc0 = {0.f, 0.f, 0.f, 0.f}, acc1 = {0.f, 0.f, 0.f, 0.f};
    float m = -INFINITY, l = 0.f;

    int beg = offs[node], end = offs[node + 1];
    for (int p = beg; p < end; ++p) {
        int j = csr_src[p];
        const float* xlrow = xl + (size_t)j * HD;
        float4 x0 = *(const float4*)(xlrow + h0);
        float4 x1 = *(const float4*)(xlrow + 256 + h0);

        float pe, t;
        t = x0.x + r0.x; pe  = a0.x * (t > 0.f ? t : NEG * t);
        t = x0.y + r0.y; pe += a0.y * (t > 0.f ? t : NEG * t);
        t = x0.z + r0.z; pe += a0.z * (t > 0.f ? t : NEG * t);
        t = x0.w + r0.w; pe += a0.w * (t > 0.f ? t : NEG * t);
        t = x1.x + r1.x; pe += a1.x * (t > 0.f ? t : NEG * t);
        t = x1.y + r1.y; pe += a1.y * (t > 0.f ? t : NEG * t);
        t = x1.z + r1.z; pe += a1.z * (t > 0.f ? t : NEG * t);
        t = x1.w + r1.w; pe += a1.w * (t > 0.f ? t : NEG * t);
        #pragma unroll
        for (int off = 32; off; off >>= 1) pe += __shfl_xor(pe, off, 64);

        float nm = fmaxf(m, pe);
        float sc = __expf(m - nm);   // m=-inf first iter -> exp(-inf)=0
        float w  = __expf(pe - nm);
        l = l * sc + w;
        acc0.x = acc0.x * sc + w * x0.x; acc0.y = acc0.y * sc + w * x0.y;
        acc0.z = acc0.z * sc + w * x0.z; acc0.w = acc0.w * sc + w * x0.w;
        acc1.x = acc1.x * sc + w * x1.x; acc1.y = acc1.y * sc + w * x1.y;
        acc1.z = acc1.z * sc + w * x1.z; acc1.w = acc1.w * sc + w * x1.w;
        m = nm;
    }

    float inv = (l > 0.f) ? 1.f / l : 0.f;   // deg==0 -> out = bias
    float4 b0 = *(const float4*)(bias + h0);
    float4 b1 = *(const float4*)(bias + 256 + h0);
    float4 o0 = {acc0.x * inv + b0.x, acc0.y * inv + b0.y,
                 acc0.z * inv + b0.z, acc0.w * inv + b0.w};
    float4 o1 = {acc1.x * inv + b1.x, acc1.y * inv + b1.y,
                 acc1.z * inv + b1.z, acc1.w * inv + b1.w};
    float* orow = out + (size_t)node * HD;
    *(float4*)(orow + h0) = o0;
    *(float4*)(orow + 256 + h0) = o1;
}

// ---------------- launch ----------------

extern "C" void kernel_launch(void* const* d_in, const int* in_sizes, int n_in,
                              void* d_out, int out_size, void* d_ws, size_t ws_size,
                              hipStream_t stream) {
    const float* x0  = (const float*)d_in[0];
    const int* eidx  = (const int*)d_in[2];
    int E = in_sizes[2] / 2;
    const int* esrc = eidx;
    const int* edst = eidx + E;

    const float* Wl[3] = {(const float*)d_in[3],  (const float*)d_in[9],  (const float*)d_in[15]};
    const float* bl[3] = {(const float*)d_in[4],  (const float*)d_in[10], (const float*)d_in[16]};
    const float* Wr[3] = {(const float*)d_in[5],  (const float*)d_in[11], (const float*)d_in[17]};
    const float* br[3] = {(const float*)d_in[6],  (const float*)d_in[12], (const float*)d_in[18]};
    const float* av[3] = {(const float*)d_in[7],  (const float*)d_in[13], (const float*)d_in[19]};
    const float* bs[3] = {(const float*)d_in[8],  (const float*)d_in[14], (const float*)d_in[20]};

    float* ws = (float*)d_ws;
    float* xl = ws;                                  // 8192*512
    float* xr = xl + (size_t)MTOT * HD;              // 8192*512
    float* xA = xr + (size_t)MTOT * HD;              // 8192*512 inter-layer activations
    int* deg    = (int*)(xA + (size_t)MTOT * HD);    // 8192
    int* offs   = deg + MTOT;                        // 8193
    int* cursor = offs + MTOT + 8;                   // 8192
    int* csr    = cursor + MTOT;                     // E

    zero_ints<<<(MTOT + 255) / 256, 256, 0, stream>>>(deg, MTOT);
    count_deg<<<(E + 255) / 256, 256, 0, stream>>>(edst, deg, E);
    scan_offsets<<<1, 1024, 0, stream>>>(deg, offs, cursor);
    scatter_edges<<<(E + 255) / 256, 256, 0, stream>>>(esrc, edst, cursor, csr, E);

    dim3 ggrid(HD / 64, MTOT / 64, 2);
    const float* xin = x0;
    float* louts[3] = {xA, xA, (float*)d_out};
    for (int L = 0; L < 3; ++L) {
        gemm_dual<<<ggrid, 256, 0, stream>>>(xin, Wl[L], bl[L], Wr[L], br[L], xl, xr);
        gat_aggregate<<<MTOT / 4, 256, 0, stream>>>(xl, xr, av[L], bs[L], offs, csr, louts[L]);
        xin = xA;
    }
}

// Round 2
// 375.777 us; speedup vs baseline: 1.5839x; 1.5839x over previous
//
#include <hip/hip_runtime.h>
#include <math.h>

#define MTOT 8192   // B*N
#define HD   512    // hidden dim
#define NEG  0.2f   // leaky relu slope

typedef __attribute__((ext_vector_type(8))) short bf16x8;
typedef __attribute__((ext_vector_type(4))) float floatx4;

__device__ inline unsigned short f2bf(float f) {
    unsigned int u = __float_as_uint(f);
    unsigned int r = (u + 0x7FFFu + ((u >> 16) & 1u)) >> 16;
    return (unsigned short)r;
}
__device__ inline float bf2f(unsigned short h) {
    return __uint_as_float(((unsigned int)h) << 16);
}

// ---------------- CSR build ----------------

__global__ void zero_ints(int* p, int n) {
    int i = blockIdx.x * 256 + threadIdx.x;
    if (i < n) p[i] = 0;
}

__global__ void count_deg(const int* __restrict__ dst, int* __restrict__ deg, int E) {
    int i = blockIdx.x * 256 + threadIdx.x;
    if (i < E) atomicAdd(&deg[dst[i]], 1);
}

__global__ __launch_bounds__(1024) void scan_offsets(const int* __restrict__ deg,
                                                     int* __restrict__ offs,
                                                     int* __restrict__ cursor) {
    __shared__ int part[1024];
    int tid = threadIdx.x;
    int base = tid * 8;
    int v[8]; int s = 0;
    #pragma unroll
    for (int i = 0; i < 8; ++i) { v[i] = deg[base + i]; s += v[i]; }
    part[tid] = s;
    __syncthreads();
    for (int off = 1; off < 1024; off <<= 1) {
        int t = (tid >= off) ? part[tid - off] : 0;
        __syncthreads();
        part[tid] += t;
        __syncthreads();
    }
    int run = (tid == 0) ? 0 : part[tid - 1];
    #pragma unroll
    for (int i = 0; i < 8; ++i) {
        offs[base + i] = run;
        cursor[base + i] = run;
        run += v[i];
    }
    if (tid == 1023) offs[MTOT] = run;
}

__global__ void scatter_edges(const int* __restrict__ src, const int* __restrict__ dst,
                              int* __restrict__ cursor, int* __restrict__ csr_src, int E) {
    int i = blockIdx.x * 256 + threadIdx.x;
    if (i < E) {
        int p = atomicAdd(&cursor[dst[i]], 1);
        csr_src[p] = src[i];
    }
}

// ---------------- split-bf16 conversions ----------------

// X fp32 [M][512] -> Ahi, Alo bf16 [M][512]
__global__ __launch_bounds__(256) void act_convert(const float* __restrict__ X,
                                                   unsigned short* __restrict__ Ahi,
                                                   unsigned short* __restrict__ Alo) {
    int i = (blockIdx.x * 256 + threadIdx.x) * 4;
    float4 v = *(const float4*)(X + i);
    ushort4 h, l;
    h.x = f2bf(v.x); l.x = f2bf(v.x - bf2f(h.x));
    h.y = f2bf(v.y); l.y = f2bf(v.y - bf2f(h.y));
    h.z = f2bf(v.z); l.z = f2bf(v.z - bf2f(h.z));
    h.w = f2bf(v.w); l.w = f2bf(v.w - bf2f(h.w));
    *(ushort4*)(Ahi + i) = h;
    *(ushort4*)(Alo + i) = l;
}

// W fp32 [K=512][N=512] row-major -> Wt_hi/Wt_lo bf16 [N][K] (transposed)
__global__ __launch_bounds__(256) void wt_convert(const float* __restrict__ W,
                                                  unsigned short* __restrict__ Whi,
                                                  unsigned short* __restrict__ Wlo) {
    __shared__ float t[32][33];
    int bx = blockIdx.x * 32;  // n base
    int by = blockIdx.y * 32;  // k base
    int tx = threadIdx.x, ty = threadIdx.y;   // block (32,8)
    for (int i = ty; i < 32; i += 8)
        t[i][tx] = W[(size_t)(by + i) * 512 + bx + tx];   // t[k_local][n_local]
    __syncthreads();
    for (int i = ty; i < 32; i += 8) {
        float v = t[tx][i];                   // W[by+tx][bx+i]
        unsigned short h = f2bf(v);
        unsigned short l = f2bf(v - bf2f(h));
        Whi[(size_t)(bx + i) * 512 + by + tx] = h;
        Wlo[(size_t)(bx + i) * 512 + by + tx] = l;
    }
}

// ---------------- split-bf16 MFMA dual GEMM ----------------
// C = A @ W + b for (Wl,bl)->xl and (Wr,br)->xr selected by blockIdx.z.
// A: [8192][512] as Ahi/Alo bf16. W pre-transposed [N][K] as hi/lo bf16.
// 128x128 tile, BK=32, 256 threads = 4 waves; wave w stages LDS tile w.

__global__ __launch_bounds__(256) void gemm_mfma_dual(
    const unsigned short* __restrict__ Ahi, const unsigned short* __restrict__ Alo,
    const unsigned short* __restrict__ Bhi_l, const unsigned short* __restrict__ Blo_l,
    const unsigned short* __restrict__ Bhi_r, const unsigned short* __restrict__ Blo_r,
    const float* __restrict__ bias_l, const float* __restrict__ bias_r,
    float* __restrict__ Cl, float* __restrict__ Cr)
{
    const unsigned short* Bhi = blockIdx.z ? Bhi_r : Bhi_l;
    const unsigned short* Blo = blockIdx.z ? Blo_r : Blo_l;
    const float* bias         = blockIdx.z ? bias_r : bias_l;
    float* C                  = blockIdx.z ? Cr : Cl;

    // tiles: 0:Ahi 1:Alo 2:Bhi 3:Blo, each 128 rows x 32 k bf16 (4096 elems)
    __shared__ __align__(16) unsigned short lds[4 * 128 * 32];

    int tid = threadIdx.x;
    int wave = tid >> 6, lane = tid & 63;
    int bm = blockIdx.y * 128, bn = blockIdx.x * 128;

    const unsigned short* gsrc[4] = {Ahi, Alo, Bhi, Blo};
    int rowbase[4] = {bm, bm, bn, bn};

    // wave-private staging base: row = rowbase + lane/4, 16B chunk = lane%4
    const unsigned short* gbase =
        gsrc[wave] + (size_t)(rowbase[wave] + (lane >> 2)) * 512 + (lane & 3) * 8;

    floatx4 acc[4][4] = {};

    int wm = wave & 1, wn = wave >> 1;
    int lr = lane & 15, lq = lane >> 4;

    for (int k0 = 0; k0 < 512; k0 += 32) {
        const unsigned short* g = gbase + k0;
        #pragma unroll
        for (int rg = 0; rg < 8; ++rg) {   // each inst: 16 rows x 64B
            __builtin_amdgcn_global_load_lds(
                (const __attribute__((address_space(1))) unsigned int*)(g + (size_t)rg * 16 * 512),
                (__attribute__((address_space(3))) unsigned int*)(&lds[wave * 4096 + rg * 512]),
                16, 0, 0);
        }
        __syncthreads();

        bf16x8 ah[4], al[4], bh[4], bl_[4];
        #pragma unroll
        for (int i = 0; i < 4; ++i) {
            int mrow = wm * 64 + i * 16 + lr;
            ah[i]  = *(const bf16x8*)&lds[0 * 4096 + mrow * 32 + lq * 8];
            al[i]  = *(const bf16x8*)&lds[1 * 4096 + mrow * 32 + lq * 8];
            int nrow = wn * 64 + i * 16 + lr;
            bh[i]  = *(const bf16x8*)&lds[2 * 4096 + nrow * 32 + lq * 8];
            bl_[i] = *(const bf16x8*)&lds[3 * 4096 + nrow * 32 + lq * 8];
        }
        #pragma unroll
        for (int i = 0; i < 4; ++i)
            #pragma unroll
            for (int j = 0; j < 4; ++j) {
                acc[i][j] = __builtin_amdgcn_mfma_f32_16x16x32_bf16(ah[i], bh[j],  acc[i][j], 0, 0, 0);
                acc[i][j] = __builtin_amdgcn_mfma_f32_16x16x32_bf16(ah[i], bl_[j], acc[i][j], 0, 0, 0);
                acc[i][j] = __builtin_amdgcn_mfma_f32_16x16x32_bf16(al[i], bh[j],  acc[i][j], 0, 0, 0);
            }
        __syncthreads();
    }

    // epilogue: C/D layout col=lane&15, row=(lane>>4)*4+r
    #pragma unroll
    for (int j = 0; j < 4; ++j) {
        int n = bn + wn * 64 + j * 16 + lr;
        float bv = bias[n];
        #pragma unroll
        for (int i = 0; i < 4; ++i) {
            int mbase = bm + wm * 64 + i * 16 + lq * 4;
            #pragma unroll
            for (int r = 0; r < 4; ++r)
                C[(size_t)(mbase + r) * 512 + n] = acc[i][j][r] + bv;
        }
    }
}

// ---------------- per-node online-softmax aggregation ----------------

__global__ __launch_bounds__(256) void gat_aggregate(
    const float* __restrict__ xl, const float* __restrict__ xr,
    const float* __restrict__ avec, const float* __restrict__ bias,
    const int* __restrict__ offs, const int* __restrict__ csr_src,
    float* __restrict__ out) {
    int node = (blockIdx.x << 2) + (threadIdx.x >> 6);
    int lane = threadIdx.x & 63;
    int h0 = lane << 2;

    float4 a0 = *(const float4*)(avec + h0);
    float4 a1 = *(const float4*)(avec + 256 + h0);
    const float* xrrow = xr + (size_t)node * HD;
    float4 r0 = *(const float4*)(xrrow + h0);
    float4 r1 = *(const float4*)(xrrow + 256 + h0);

    float4 acc0 = {0.f, 0.f, 0.f, 0.f}, acc1 = {0.f, 0.f, 0.f, 0.f};
    float m = -INFINITY, l = 0.f;

    int beg = offs[node], end = offs[node + 1];
    for (int p = beg; p < end; ++p) {
        int j = csr_src[p];
        const float* xlrow = xl + (size_t)j * HD;
        float4 x0 = *(const float4*)(xlrow + h0);
        float4 x1 = *(const float4*)(xlrow + 256 + h0);

        float pe, t;
        t = x0.x + r0.x; pe  = a0.x * (t > 0.f ? t : NEG * t);
        t = x0.y + r0.y; pe += a0.y * (t > 0.f ? t : NEG * t);
        t = x0.z + r0.z; pe += a0.z * (t > 0.f ? t : NEG * t);
        t = x0.w + r0.w; pe += a0.w * (t > 0.f ? t : NEG * t);
        t = x1.x + r1.x; pe += a1.x * (t > 0.f ? t : NEG * t);
        t = x1.y + r1.y; pe += a1.y * (t > 0.f ? t : NEG * t);
        t = x1.z + r1.z; pe += a1.z * (t > 0.f ? t : NEG * t);
        t = x1.w + r1.w; pe += a1.w * (t > 0.f ? t : NEG * t);
        #pragma unroll
        for (int off = 32; off; off >>= 1) pe += __shfl_xor(pe, off, 64);

        float nm = fmaxf(m, pe);
        float sc = __expf(m - nm);
        float w  = __expf(pe - nm);
        l = l * sc + w;
        acc0.x = acc0.x * sc + w * x0.x; acc0.y = acc0.y * sc + w * x0.y;
        acc0.z = acc0.z * sc + w * x0.z; acc0.w = acc0.w * sc + w * x0.w;
        acc1.x = acc1.x * sc + w * x1.x; acc1.y = acc1.y * sc + w * x1.y;
        acc1.z = acc1.z * sc + w * x1.z; acc1.w = acc1.w * sc + w * x1.w;
        m = nm;
    }

    float inv = (l > 0.f) ? 1.f / l : 0.f;
    float4 b0 = *(const float4*)(bias + h0);
    float4 b1 = *(const float4*)(bias + 256 + h0);
    float4 o0 = {acc0.x * inv + b0.x, acc0.y * inv + b0.y,
                 acc0.z * inv + b0.z, acc0.w * inv + b0.w};
    float4 o1 = {acc1.x * inv + b1.x, acc1.y * inv + b1.y,
                 acc1.z * inv + b1.z, acc1.w * inv + b1.w};
    float* orow = out + (size_t)node * HD;
    *(float4*)(orow + h0) = o0;
    *(float4*)(orow + 256 + h0) = o1;
}

// ---------------- launch ----------------

extern "C" void kernel_launch(void* const* d_in, const int* in_sizes, int n_in,
                              void* d_out, int out_size, void* d_ws, size_t ws_size,
                              hipStream_t stream) {
    const float* x0 = (const float*)d_in[0];
    const int* eidx = (const int*)d_in[2];
    int E = in_sizes[2] / 2;
    const int* esrc = eidx;
    const int* edst = eidx + E;

    const float* Wl[3] = {(const float*)d_in[3],  (const float*)d_in[9],  (const float*)d_in[15]};
    const float* bl[3] = {(const float*)d_in[4],  (const float*)d_in[10], (const float*)d_in[16]};
    const float* Wr[3] = {(const float*)d_in[5],  (const float*)d_in[11], (const float*)d_in[17]};
    const float* br[3] = {(const float*)d_in[6],  (const float*)d_in[12], (const float*)d_in[18]};
    const float* av[3] = {(const float*)d_in[7],  (const float*)d_in[13], (const float*)d_in[19]};
    const float* bs[3] = {(const float*)d_in[8],  (const float*)d_in[14], (const float*)d_in[20]};

    // workspace layout
    char* w = (char*)d_ws;
    unsigned short* Ahi = (unsigned short*)w; w += (size_t)MTOT * HD * 2;
    unsigned short* Alo = (unsigned short*)w; w += (size_t)MTOT * HD * 2;
    unsigned short* Wt[12];   // L*4 + {0:Wl_hi,1:Wl_lo,2:Wr_hi,3:Wr_lo}
    for (int i = 0; i < 12; ++i) { Wt[i] = (unsigned short*)w; w += (size_t)HD * HD * 2; }
    float* xl = (float*)w; w += (size_t)MTOT * HD * 4;
    float* xr = (float*)w; w += (size_t)MTOT * HD * 4;
    int* deg    = (int*)w;
    int* offs   = deg + MTOT;
    int* cursor = offs + MTOT + 8;
    int* csr    = cursor + MTOT;
    float* act  = (float*)d_out;   // inter-layer activations live in d_out

    // weight split+transpose (once per call)
    dim3 wtg(16, 16), wtb(32, 8);
    for (int L = 0; L < 3; ++L) {
        wt_convert<<<wtg, wtb, 0, stream>>>(Wl[L], Wt[L * 4 + 0], Wt[L * 4 + 1]);
        wt_convert<<<wtg, wtb, 0, stream>>>(Wr[L], Wt[L * 4 + 2], Wt[L * 4 + 3]);
    }

    // CSR build
    zero_ints<<<(MTOT + 255) / 256, 256, 0, stream>>>(deg, MTOT);
    count_deg<<<(E + 255) / 256, 256, 0, stream>>>(edst, deg, E);
    scan_offsets<<<1, 1024, 0, stream>>>(deg, offs, cursor);
    scatter_edges<<<(E + 255) / 256, 256, 0, stream>>>(esrc, edst, cursor, csr, E);

    dim3 ggrid(HD / 128, MTOT / 128, 2);
    const float* xin = x0;
    for (int L = 0; L < 3; ++L) {
        act_convert<<<(MTOT * HD / 4 + 255) / 256, 256, 0, stream>>>(xin, Ahi, Alo);
        gemm_mfma_dual<<<ggrid, 256, 0, stream>>>(Ahi, Alo,
                                                  Wt[L * 4 + 0], Wt[L * 4 + 1],
                                                  Wt[L * 4 + 2], Wt[L * 4 + 3],
                                                  bl[L], br[L], xl, xr);
        gat_aggregate<<<MTOT / 4, 256, 0, stream>>>(xl, xr, av[L], bs[L], offs, csr,
                                                    (L == 2) ? (float*)d_out : act);
        xin = act;
    }
}